// Round 15
// baseline (221.116 us; speedup 1.0000x reference)
//
#include <hip/hip_runtime.h>
#include <math.h>

#define NUM_GRAPHS 256
#define LAMBDA 0.01f

typedef int            v4i __attribute__((ext_vector_type(4)));
typedef float          v4f __attribute__((ext_vector_type(4)));
typedef unsigned int   v4u __attribute__((ext_vector_type(4)));
typedef unsigned short v8h __attribute__((ext_vector_type(8)));

__device__ __forceinline__ unsigned short f2bf_rne(float f) {
    unsigned int u = __float_as_uint(f);
    u = u + 0x7fffu + ((u >> 16) & 1u);
    return (unsigned short)(u >> 16);
}

// sum of squared diffs of 8 bf16 pairs packed in 4 dwords (exact unpack)
__device__ __forceinline__ float bfdiff_sq(v4u a, v4u b) {
    float s = 0.0f;
    #pragma unroll
    for (int k = 0; k < 4; ++k) {
        float alo = __uint_as_float(a[k] << 16);
        float ahi = __uint_as_float(a[k] & 0xffff0000u);
        float blo = __uint_as_float(b[k] << 16);
        float bhi = __uint_as_float(b[k] & 0xffff0000u);
        float d1 = alo - blo;
        float d2 = ahi - bhi;
        s += d1 * d1;
        s += d2 * d2;
    }
    return s;
}

// ---------------------------------------------------------------------------
// Dispatch 1: x (f32) -> xh (bf16 RNE); zeroes deg/energy/cnt/ctr region.
// ---------------------------------------------------------------------------
__global__ void k_cvt(const float* __restrict__ x, v8h* __restrict__ xh,
                      float* __restrict__ zr, int zcount8, long total8) {
    long j = (long)blockIdx.x * blockDim.x + threadIdx.x;
    if (j < total8) {
        const v4f* xp = (const v4f*)(x + j * 8);
        v4f a = xp[0], b = xp[1];
        v8h o;
        o[0] = f2bf_rne(a[0]); o[1] = f2bf_rne(a[1]);
        o[2] = f2bf_rne(a[2]); o[3] = f2bf_rne(a[3]);
        o[4] = f2bf_rne(b[0]); o[5] = f2bf_rne(b[1]);
        o[6] = f2bf_rne(b[2]); o[7] = f2bf_rne(b[3]);
        __builtin_nontemporal_store(o, xh + j);
    }
    if (j < zcount8) {
        v4f z = {0.0f, 0.0f, 0.0f, 0.0f};
        v4f* zp = (v4f*)(zr + j * 8);
        zp[0] = z; zp[1] = z;
    }
}

// ---------------------------------------------------------------------------
// Dispatch 2 (gather, r14-verbatim body): sq[e] = ||x_r - x_c||^2 (bf16) and
// deg[r] += 1.  Wave = 8 groups x 8 lanes, 8 contiguous edges/group ->
// 16 independent 128B gathers in flight.  Pinned at ~72us by device-level
// random-gather request throughput (proven invariant r10-r14); deg atomics
// ride for free; ~42MB dirty-eviction write waste accepted (r12: time-free).
// ---------------------------------------------------------------------------
__global__ void __launch_bounds__(256, 4)
k_gather(const int* __restrict__ row, const int* __restrict__ col,
         const v4u* __restrict__ xh4, float* __restrict__ deg,
         float* __restrict__ sq, int E) {
    const int lane   = threadIdx.x & 63;
    const int lane8  = lane & 7;
    const int gi     = lane >> 3;
    const int wave   = (blockIdx.x * blockDim.x + threadIdx.x) >> 6;
    const int nwaves = (gridDim.x * blockDim.x) >> 6;
    const int E64    = E >> 6;

    for (int t = wave; t < E64; t += nwaves) {
        const int ebase = t * 64 + gi * 8;

        v4i rv0 = __builtin_nontemporal_load((const v4i*)(row + ebase));
        v4i rv1 = __builtin_nontemporal_load((const v4i*)(row + ebase + 4));
        v4i cv0 = __builtin_nontemporal_load((const v4i*)(col + ebase));
        v4i cv1 = __builtin_nontemporal_load((const v4i*)(col + ebase + 4));

        v4u a0 = xh4[(long)rv0[0] * 8 + lane8];
        v4u b0 = xh4[(long)cv0[0] * 8 + lane8];
        v4u a1 = xh4[(long)rv0[1] * 8 + lane8];
        v4u b1 = xh4[(long)cv0[1] * 8 + lane8];
        v4u a2 = xh4[(long)rv0[2] * 8 + lane8];
        v4u b2 = xh4[(long)cv0[2] * 8 + lane8];
        v4u a3 = xh4[(long)rv0[3] * 8 + lane8];
        v4u b3 = xh4[(long)cv0[3] * 8 + lane8];
        v4u a4 = xh4[(long)rv1[0] * 8 + lane8];
        v4u b4 = xh4[(long)cv1[0] * 8 + lane8];
        v4u a5 = xh4[(long)rv1[1] * 8 + lane8];
        v4u b5 = xh4[(long)cv1[1] * 8 + lane8];
        v4u a6 = xh4[(long)rv1[2] * 8 + lane8];
        v4u b6 = xh4[(long)cv1[2] * 8 + lane8];
        v4u a7 = xh4[(long)rv1[3] * 8 + lane8];
        v4u b7 = xh4[(long)cv1[3] * 8 + lane8];

        float s0 = bfdiff_sq(a0, b0);
        float s1 = bfdiff_sq(a1, b1);
        float s2 = bfdiff_sq(a2, b2);
        float s3 = bfdiff_sq(a3, b3);
        float s4 = bfdiff_sq(a4, b4);
        float s5 = bfdiff_sq(a5, b5);
        float s6 = bfdiff_sq(a6, b6);
        float s7 = bfdiff_sq(a7, b7);

        s0 += __shfl_xor(s0, 1); s1 += __shfl_xor(s1, 1);
        s2 += __shfl_xor(s2, 1); s3 += __shfl_xor(s3, 1);
        s4 += __shfl_xor(s4, 1); s5 += __shfl_xor(s5, 1);
        s6 += __shfl_xor(s6, 1); s7 += __shfl_xor(s7, 1);
        s0 += __shfl_xor(s0, 2); s1 += __shfl_xor(s1, 2);
        s2 += __shfl_xor(s2, 2); s3 += __shfl_xor(s3, 2);
        s4 += __shfl_xor(s4, 2); s5 += __shfl_xor(s5, 2);
        s6 += __shfl_xor(s6, 2); s7 += __shfl_xor(s7, 2);
        s0 += __shfl_xor(s0, 4); s1 += __shfl_xor(s1, 4);
        s2 += __shfl_xor(s2, 4); s3 += __shfl_xor(s3, 4);
        s4 += __shfl_xor(s4, 4); s5 += __shfl_xor(s5, 4);
        s6 += __shfl_xor(s6, 4); s7 += __shfl_xor(s7, 4);

        if (lane8 == 0) {
            v4f sv; sv[0] = s0; sv[1] = s1; sv[2] = s2; sv[3] = s3;
            __builtin_nontemporal_store(sv, (v4f*)(sq + ebase));
        } else if (lane8 == 1) {
            v4f sv; sv[0] = s4; sv[1] = s5; sv[2] = s6; sv[3] = s7;
            __builtin_nontemporal_store(sv, (v4f*)(sq + ebase + 4));
        }
        int rr = (lane8 < 4) ? rv0[lane8] : rv1[lane8 - 4];
        atomicAdd(&deg[rr], 1.0f);
    }

    for (int e = (E64 << 6) + wave; e < E; e += nwaves) {
        int r = row[e], c = col[e];
        v4u a = xh4[(long)r * 8 + lane8];
        v4u b = xh4[(long)c * 8 + lane8];
        float s = bfdiff_sq(a, b);
        s += __shfl_xor(s, 1);
        s += __shfl_xor(s, 2);
        s += __shfl_xor(s, 4);
        if (lane == 0) sq[e] = s;
        if (lane == 8) atomicAdd(&deg[r], 1.0f);
    }
}

// ---------------------------------------------------------------------------
// Dispatch 3 (bin + final): streams row/col/sq; per edge gathers deg[r],
// deg[c], batch[r] (L2-resident, dis = rsqrt inline — k_dis pass
// eliminated); LDS histograms for energy AND edge-count; atomic flush; the
// LAST block to finish (device-scope counter + threadfence) runs the fused
// CE + mean(energy/cnt) finale — k_final pass eliminated.
// ---------------------------------------------------------------------------
__global__ void __launch_bounds__(256)
k_bin2(const int* __restrict__ row, const int* __restrict__ col,
       const float* __restrict__ sq, const float* __restrict__ deg,
       const int* __restrict__ batch, float* __restrict__ g_energy,
       float* __restrict__ cnt, int* __restrict__ ctr,
       const float* __restrict__ logits, const int* __restrict__ labels,
       float* __restrict__ out, int E, int nblocks) {
    __shared__ float lbin[NUM_GRAPHS];
    __shared__ float lcnt[NUM_GRAPHS];
    lbin[threadIdx.x] = 0.0f;
    lcnt[threadIdx.x] = 0.0f;
    __syncthreads();

    const int i = blockIdx.x * blockDim.x + threadIdx.x;
    const int stride = gridDim.x * blockDim.x;
    const int E4 = E >> 2;
    const v4i* r4 = (const v4i*)row;
    const v4i* c4 = (const v4i*)col;
    const v4f* s4 = (const v4f*)sq;

    for (int k = i; k < E4; k += stride) {
        v4i r = __builtin_nontemporal_load(&r4[k]);
        v4i c = __builtin_nontemporal_load(&c4[k]);
        v4f s = __builtin_nontemporal_load(&s4[k]);
        #pragma unroll
        for (int j = 0; j < 4; ++j) {
            float dr = deg[r[j]];
            float dc = deg[c[j]];
            int g = batch[r[j]];
            float nr = ((dr > 0.0f) ? rsqrtf(dr) : 0.0f) *
                       ((dc > 0.0f) ? rsqrtf(dc) : 0.0f);
            atomicAdd(&lbin[g], nr * s[j]);
            atomicAdd(&lcnt[g], 1.0f);
        }
    }
    for (int e = (E4 << 2) + i; e < E; e += stride) {
        float dr = deg[row[e]];
        float dc = deg[col[e]];
        int g = batch[row[e]];
        float nr = ((dr > 0.0f) ? rsqrtf(dr) : 0.0f) *
                   ((dc > 0.0f) ? rsqrtf(dc) : 0.0f);
        atomicAdd(&lbin[g], nr * sq[e]);
        atomicAdd(&lcnt[g], 1.0f);
    }

    __syncthreads();
    atomicAdd(&g_energy[threadIdx.x], lbin[threadIdx.x]);
    atomicAdd(&cnt[threadIdx.x], lcnt[threadIdx.x]);
    __threadfence();
    __syncthreads();

    __shared__ int amLast;
    if (threadIdx.x == 0) {
        amLast = (atomicAdd(ctr, 1) == nblocks - 1) ? 1 : 0;
    }
    __syncthreads();
    if (!amLast) return;
    __threadfence();

    // ---- finale (one block): CE + mean(energy / max(cnt,1)) ----
    const int t = threadIdx.x;  // 256 threads = NUM_GRAPHS
    float ge = __hip_atomic_load(&g_energy[t], __ATOMIC_ACQUIRE,
                                 __HIP_MEMORY_SCOPE_AGENT);
    float cn = __hip_atomic_load(&cnt[t], __ATOMIC_ACQUIRE,
                                 __HIP_MEMORY_SCOPE_AGENT);

    const float* lg = logits + t * 10;
    float m = -INFINITY;
    #pragma unroll
    for (int j = 0; j < 10; ++j) m = fmaxf(m, lg[j]);
    float sum = 0.0f;
    #pragma unroll
    for (int j = 0; j < 10; ++j) sum += expf(lg[j] - m);
    float lse = m + logf(sum);
    float ce = lse - lg[labels[t]];

    float sm = ge / fmaxf(cn, 1.0f);

    float v = ce + LAMBDA * sm;
    #pragma unroll
    for (int mk = 1; mk < 64; mk <<= 1) v += __shfl_xor(v, mk);

    __shared__ float wsum[4];
    if ((t & 63) == 0) wsum[t >> 6] = v;
    __syncthreads();
    if (t == 0) out[0] = (wsum[0] + wsum[1] + wsum[2] + wsum[3]) * (1.0f / 256.0f);
}

// ---------------------------------------------------------------------------
// Minimal-ws fallback chain (f32 direct path, known-passing shape).
// ---------------------------------------------------------------------------
__global__ void k_deg_f(const int* __restrict__ row, float* __restrict__ deg, int E) {
    const int i = blockIdx.x * blockDim.x + threadIdx.x;
    const int stride = gridDim.x * blockDim.x;
    for (int e = i; e < E; e += stride) atomicAdd(&deg[row[e]], 1.0f);
}

__global__ void k_dis(float* __restrict__ deg_dis, const int* __restrict__ batch,
                      float* __restrict__ cnt, int N) {
    int i = blockIdx.x * blockDim.x + threadIdx.x;
    bool valid = (i < N);
    float d = valid ? deg_dis[i] : 0.0f;
    int g = valid ? batch[i] : -1;
    if (valid) deg_dis[i] = (d > 0.0f) ? rsqrtf(d) : 0.0f;

    int gmin = g, gmax = g;
    #pragma unroll
    for (int m = 1; m < 64; m <<= 1) {
        gmin = min(gmin, __shfl_xor(gmin, m));
        gmax = max(gmax, __shfl_xor(gmax, m));
    }
    if (gmin == gmax && gmin >= 0) {
        float s = d;
        #pragma unroll
        for (int m = 1; m < 64; m <<= 1) s += __shfl_xor(s, m);
        if ((threadIdx.x & 63) == 0) atomicAdd(&cnt[g], s);
    } else if (valid) {
        atomicAdd(&cnt[g], d);
    }
}

__global__ void k_energy(const int* __restrict__ row, const int* __restrict__ col,
                         const float4* __restrict__ x4, const float* __restrict__ dis,
                         const int* __restrict__ batch, float* __restrict__ g_energy,
                         int E) {
    __shared__ float lbin[NUM_GRAPHS];
    lbin[threadIdx.x] = 0.0f;
    __syncthreads();

    const int lane16 = threadIdx.x & 15;
    const int group = (blockIdx.x * blockDim.x + threadIdx.x) >> 4;
    const int ngroups = (gridDim.x * blockDim.x) >> 4;

    for (int e = group; e < E; e += ngroups) {
        int r = row[e];
        int c = col[e];
        float4 a = x4[(long)r * 16 + lane16];
        float4 b = x4[(long)c * 16 + lane16];
        float nr = dis[r] * dis[c];
        int g = batch[r];
        float dx = a.x - b.x, dy = a.y - b.y, dz = a.z - b.z, dw = a.w - b.w;
        float s = dx * dx + dy * dy + dz * dz + dw * dw;
        s += __shfl_xor(s, 1);
        s += __shfl_xor(s, 2);
        s += __shfl_xor(s, 4);
        s += __shfl_xor(s, 8);
        if (lane16 == 0) atomicAdd(&lbin[g], nr * s);
    }

    __syncthreads();
    float v = lbin[threadIdx.x];
    if (v != 0.0f) atomicAdd(&g_energy[threadIdx.x], v);
}

__global__ void k_final(const float* __restrict__ logits, const int* __restrict__ labels,
                        const float* __restrict__ g_energy, const float* __restrict__ cnt,
                        float* __restrict__ out) {
    const int t = threadIdx.x;
    const float* lg = logits + t * 10;

    float m = -INFINITY;
    #pragma unroll
    for (int j = 0; j < 10; ++j) m = fmaxf(m, lg[j]);
    float sum = 0.0f;
    #pragma unroll
    for (int j = 0; j < 10; ++j) sum += expf(lg[j] - m);
    float lse = m + logf(sum);
    float ce = lse - lg[labels[t]];

    float sm = g_energy[t] / fmaxf(cnt[t], 1.0f);

    float v = ce + LAMBDA * sm;
    #pragma unroll
    for (int mk = 1; mk < 64; mk <<= 1) v += __shfl_xor(v, mk);

    __shared__ float wsum[4];
    if ((t & 63) == 0) wsum[t >> 6] = v;
    __syncthreads();
    if (t == 0) out[0] = (wsum[0] + wsum[1] + wsum[2] + wsum[3]) * (1.0f / 256.0f);
}

// ---------------------------------------------------------------------------
extern "C" void kernel_launch(void* const* d_in, const int* in_sizes, int n_in,
                              void* d_out, int out_size, void* d_ws, size_t ws_size,
                              hipStream_t stream) {
    const float* logits = (const float*)d_in[0];
    const int* labels   = (const int*)d_in[1];
    const float* x      = (const float*)d_in[2];
    const int* edge_idx = (const int*)d_in[3];
    const int* batch    = (const int*)d_in[4];

    const int N = in_sizes[2] / 64;   // 100000
    const int E = in_sizes[3] / 2;    // 1200000

    const int* row = edge_idx;
    const int* col = edge_idx + E;

    // ws: [deg : N][energy : 256][cnt : 256][ctr+pad : 64][sq : E][xh : 64N bf16]
    float* deg      = (float*)d_ws;
    float* g_energy = deg + N;
    float* cnt      = g_energy + NUM_GRAPHS;
    int*   ctr      = (int*)(cnt + NUM_GRAPHS);
    float* sq       = cnt + NUM_GRAPHS + 64;
    unsigned short* xh = (unsigned short*)(sq + E);

    const size_t zfloats  = (size_t)N + 2 * NUM_GRAPHS + 64;        // deg..ctr
    const size_t need_fast = (zfloats + (size_t)E) * sizeof(float)
                           + (size_t)N * 64 * sizeof(unsigned short);

    const int BIN_BLOCKS = 512;

    if (ws_size >= need_fast) {
        const long total8 = (long)N * 8;                 // bf16x8 chunks
        const int zcount8 = (int)((zfloats + 7) / 8);
        const int cvt_blocks = (int)((total8 + 255) / 256);
        k_cvt<<<cvt_blocks, 256, 0, stream>>>(x, (v8h*)xh, deg, zcount8, total8);
        k_gather<<<2048, 256, 0, stream>>>(row, col, (const v4u*)xh, deg, sq, E);
        k_bin2<<<BIN_BLOCKS, 256, 0, stream>>>(row, col, sq, deg, batch, g_energy,
                                               cnt, ctr, logits, labels,
                                               (float*)d_out, E, BIN_BLOCKS);
    } else {
        // fallback: f32 direct path (4 dispatches + memset)
        (void)hipMemsetAsync(d_ws, 0, zfloats * sizeof(float), stream);
        k_deg_f<<<2048, 256, 0, stream>>>(row, deg, E);
        k_dis<<<(N + 255) / 256, 256, 0, stream>>>(deg, batch, cnt, N);
        k_energy<<<2048, 256, 0, stream>>>(row, col, (const float4*)x, deg, batch,
                                           g_energy, E);
        k_final<<<1, 256, 0, stream>>>(logits, labels, g_energy, cnt, (float*)d_out);
    }
}